// Round 2
// baseline (28833.136 us; speedup 1.0000x reference)
//
#include <hip/hip_runtime.h>
#include <stdint.h>

// LSTM: 2-layer LSTMCell H=2048, T=2048, future=128.
// R2: flag-based low-traffic exchange + named-float4 register-resident weights
//     + prefetch-double-buffered fp32 GEMM for the layer-2 input projection.
//
// Workspace layout (~97 MB):
//   flags1 [256] u32   @ 0        (monotonic steps-completed per block, layer1)
//   flags2 [256] u32   @ 4096
//   vals1  [2][2048] f32bits @ 8192    (h1 exchange, double-buffered by parity)
//   vals2  [2][2048] f32bits @ 32768
//   H1     [2048][2048] f32 @ 65536
//   H2     [2048][2048] f32 @ 65536+16M
//   IG2    [2048][8192] f32 @ 65536+32M
//   c1f    [2048] f32       @ 65536+96M
//   c2f    [2048] f32       @ 65536+96M+8192

typedef unsigned long long u64;
typedef unsigned int u32;

#define HD 2048
#define TT 2048
#define FUT 128
#define G4 8192

#define LD4(p) (*reinterpret_cast<const float4*>(p))

__device__ __forceinline__ float sigm_(float x) {
    return 1.0f / (1.0f + __expf(-x));
}
__device__ __forceinline__ float tanh_(float x) {
    float xc = fminf(fmaxf(x, -15.0f), 15.0f);
    float e = __expf(2.0f * xc);
    return 1.0f - 2.0f / (e + 1.0f);
}

// wave0 polls all 256 per-block flags until flag >= tag. Bounded (no hangs).
__device__ __forceinline__ void poll_flags(const u32* flags, u32 tag, int tid) {
    if (tid < 64) {
        const u64* f = (const u64*)flags;
        int guard = 0;
        for (;;) {
            u64 a = __hip_atomic_load(f + tid,      __ATOMIC_RELAXED, __HIP_MEMORY_SCOPE_AGENT);
            u64 b = __hip_atomic_load(f + 64 + tid, __ATOMIC_RELAXED, __HIP_MEMORY_SCOPE_AGENT);
            int ok = ((u32)a >= tag) & ((u32)(a >> 32) >= tag) &
                     ((u32)b >= tag) & ((u32)(b >> 32) >= tag);
            if (__all(ok)) break;
            __builtin_amdgcn_s_sleep(1);
            if (++guard > (1 << 18)) break;   // fail visibly, never hang
        }
    }
}

__global__ void init_flags_kernel(u32* p) {
    p[blockIdx.x * 256 + threadIdx.x] = 0;
}

// ---------------------------------------------------------------------------
// Phase A / C: one-layer recurrence, weights in named float4 VGPRs.
// 256 blocks x 1024 threads. Block b owns h outputs j=b*8..b*8+7 (32 gate rows).
// Thread (chunk=tid>>5, br=tid&31): 64 weights of row(br), cols chunk*64..+63.
// ---------------------------------------------------------------------------
__global__ void __launch_bounds__(1024, 4)
recur_kernel(const float* __restrict__ Wrec,
             const float* __restrict__ aiv,     // w_ih1 or nullptr
             const float* __restrict__ ba,
             const float* __restrict__ bb,
             const float* __restrict__ xseq,    // input or nullptr
             const float* __restrict__ ig2,     // nullptr or [TT][G4]
             u32* __restrict__ flags,
             u32* __restrict__ vals,            // [2][HD] f32 bits
             float* __restrict__ hist,
             float* __restrict__ cfin)
{
    __shared__ float lds_h[HD];
    __shared__ float lds_p[32][33];
    __shared__ float lds_g[32];
    __shared__ float lds_x[TT];

    const int tid = threadIdx.x;
    const int br = tid & 31;
    const int chunk = tid >> 5;
    const int gate = br >> 3;
    const int jj = br & 7;
    const int row = gate * HD + blockIdx.x * 8 + jj;
    const int e0 = tid * 2, e1 = tid * 2 + 1;

    // resident weights: 16 NAMED float4s (guaranteed VGPR, no SROA dependence)
    const float* wsrc = Wrec + (size_t)row * HD + chunk * 64;
    float4 w0 = LD4(wsrc +  0), w1 = LD4(wsrc +  4), w2  = LD4(wsrc +  8), w3  = LD4(wsrc + 12);
    float4 w4 = LD4(wsrc + 16), w5 = LD4(wsrc + 20), w6  = LD4(wsrc + 24), w7  = LD4(wsrc + 28);
    float4 w8 = LD4(wsrc + 32), w9 = LD4(wsrc + 36), w10 = LD4(wsrc + 40), w11 = LD4(wsrc + 44);
    float4 w12 = LD4(wsrc + 48), w13 = LD4(wsrc + 52), w14 = LD4(wsrc + 56), w15 = LD4(wsrc + 60);

    const float myb = ba[row] + bb[row];
    const float myaiv = aiv ? aiv[row] : 0.0f;

    if (xseq) { lds_x[e0] = xseq[e0]; lds_x[e1] = xseq[e1]; }

    float c = 0.0f;   // cell state lives in wave0 lanes 0..7

    #pragma unroll 1
    for (int t = 0; t < TT; ++t) {
        // prefetch add-in early (hides L3/HBM latency under poll+stage)
        float addv = 0.0f;
        if (ig2 && tid < 32) addv = ig2[(size_t)t * G4 + row];

        if (t == 0) {
            lds_h[e0] = 0.0f; lds_h[e1] = 0.0f;
            __syncthreads();
        } else {
            poll_flags(flags, (u32)t, tid);
            __syncthreads();
            const u64* v64 = (const u64*)(vals + (size_t)((t - 1) & 1) * HD);
            u64 v = __hip_atomic_load(v64 + tid, __ATOMIC_RELAXED, __HIP_MEMORY_SCOPE_AGENT);
            lds_h[e0] = __uint_as_float((u32)v);
            lds_h[e1] = __uint_as_float((u32)(v >> 32));
            __syncthreads();
        }
        if (!ig2 && tid < 32) addv = myaiv * lds_x[t];

        // partial dot: 64 FMAs against LDS-broadcast h
        const float* hc = lds_h + chunk * 64;
        float a0 = 0, a1 = 0, a2 = 0, a3 = 0;
        #define ACC4(W, i) { float4 hv = LD4(hc + 4 * (i)); \
            a0 = fmaf(W.x, hv.x, a0); a1 = fmaf(W.y, hv.y, a1); \
            a2 = fmaf(W.z, hv.z, a2); a3 = fmaf(W.w, hv.w, a3); }
        ACC4(w0, 0)  ACC4(w1, 1)  ACC4(w2, 2)   ACC4(w3, 3)
        ACC4(w4, 4)  ACC4(w5, 5)  ACC4(w6, 6)   ACC4(w7, 7)
        ACC4(w8, 8)  ACC4(w9, 9)  ACC4(w10, 10) ACC4(w11, 11)
        ACC4(w12, 12) ACC4(w13, 13) ACC4(w14, 14) ACC4(w15, 15)
        #undef ACC4
        lds_p[chunk][br] = (a0 + a1) + (a2 + a3);
        __syncthreads();

        if (tid < 32) {   // wave0: reduce 32 chunks, activate, cell update, publish
            float s0 = 0, s1 = 0, s2 = 0, s3 = 0;
            #pragma unroll
            for (int cc = 0; cc < 32; cc += 4) {
                s0 += lds_p[cc + 0][br];
                s1 += lds_p[cc + 1][br];
                s2 += lds_p[cc + 2][br];
                s3 += lds_p[cc + 3][br];
            }
            float gsum = (s0 + s1) + (s2 + s3) + myb + addv;
            lds_g[br] = (gate == 2) ? tanh_(gsum) : sigm_(gsum);
            if (br < 8) {
                float gi = lds_g[br], gf = lds_g[8 + br];
                float gg = lds_g[16 + br], go = lds_g[24 + br];
                c = gf * c + gi * gg;
                float h = go * tanh_(c);
                hist[(size_t)t * HD + blockIdx.x * 8 + br] = h;
                __hip_atomic_store(vals + (size_t)(t & 1) * HD + blockIdx.x * 8 + br,
                                   __float_as_uint(h), __ATOMIC_RELAXED, __HIP_MEMORY_SCOPE_AGENT);
            }
        }
        // release: value stores (same wave, earlier instr) drain before flag store
        if (tid == 0)
            __hip_atomic_store(flags + blockIdx.x, (u32)(t + 1),
                               __ATOMIC_RELEASE, __HIP_MEMORY_SCOPE_AGENT);
    }
    if (tid < 8) cfin[blockIdx.x * 8 + tid] = c;
}

// ---------------------------------------------------------------------------
// Phase B: IG2[t][r] = sum_k H1[t][k] * W_ih2[r][k]  (fp32, 128x128 tile,
// BK=16, register prefetch double-buffering)
// ---------------------------------------------------------------------------
__global__ void __launch_bounds__(256)
ig2_gemm_kernel(const float* __restrict__ H1h, const float* __restrict__ W,
                float* __restrict__ IG2)
{
    __shared__ float As[16][132];
    __shared__ float Bs[16][132];
    const int tid = threadIdx.x;
    const int tx = tid & 15;
    const int ty = tid >> 4;
    const int r0 = blockIdx.x * 128;
    const int t0 = blockIdx.y * 128;
    const int stt = tid & 127;
    const int skc = tid >> 7;
    const int kb = skc * 8;

    float acc[8][8];
    #pragma unroll
    for (int i = 0; i < 8; ++i)
        #pragma unroll
        for (int j = 0; j < 8; ++j) acc[i][j] = 0.0f;

    const float* pa = H1h + (size_t)(t0 + stt) * HD + kb;
    const float* pb = W   + (size_t)(r0 + stt) * HD + kb;
    float4 va0 = LD4(pa), va1 = LD4(pa + 4);
    float4 vb0 = LD4(pb), vb1 = LD4(pb + 4);
    pa += 16; pb += 16;

    #pragma unroll 1
    for (int k0 = 0; k0 < HD; k0 += 16) {
        __syncthreads();   // previous tile's readers done
        As[kb + 0][stt] = va0.x; As[kb + 1][stt] = va0.y; As[kb + 2][stt] = va0.z; As[kb + 3][stt] = va0.w;
        As[kb + 4][stt] = va1.x; As[kb + 5][stt] = va1.y; As[kb + 6][stt] = va1.z; As[kb + 7][stt] = va1.w;
        Bs[kb + 0][stt] = vb0.x; Bs[kb + 1][stt] = vb0.y; Bs[kb + 2][stt] = vb0.z; Bs[kb + 3][stt] = vb0.w;
        Bs[kb + 4][stt] = vb1.x; Bs[kb + 5][stt] = vb1.y; Bs[kb + 6][stt] = vb1.z; Bs[kb + 7][stt] = vb1.w;
        __syncthreads();
        if (k0 + 16 < HD) {   // prefetch next tile into regs; hidden under FMAs
            va0 = LD4(pa); va1 = LD4(pa + 4);
            vb0 = LD4(pb); vb1 = LD4(pb + 4);
            pa += 16; pb += 16;
        }
        #pragma unroll
        for (int kk = 0; kk < 16; ++kk) {
            float4 fa0 = LD4(&As[kk][ty * 8]);
            float4 fa1 = LD4(&As[kk][ty * 8 + 4]);
            float4 fb0 = LD4(&Bs[kk][tx * 8]);
            float4 fb1 = LD4(&Bs[kk][tx * 8 + 4]);
            float av[8] = {fa0.x, fa0.y, fa0.z, fa0.w, fa1.x, fa1.y, fa1.z, fa1.w};
            float bv[8] = {fb0.x, fb0.y, fb0.z, fb0.w, fb1.x, fb1.y, fb1.z, fb1.w};
            #pragma unroll
            for (int i = 0; i < 8; ++i)
                #pragma unroll
                for (int j = 0; j < 8; ++j)
                    acc[i][j] = fmaf(av[i], bv[j], acc[i][j]);
        }
    }
    #pragma unroll
    for (int i = 0; i < 8; ++i) {
        float* pc = IG2 + (size_t)(t0 + ty * 8 + i) * G4 + (r0 + tx * 8);
        *reinterpret_cast<float4*>(pc)     = make_float4(acc[i][0], acc[i][1], acc[i][2], acc[i][3]);
        *reinterpret_cast<float4*>(pc + 4) = make_float4(acc[i][4], acc[i][5], acc[i][6], acc[i][7]);
    }
}

// ---------------------------------------------------------------------------
// Phase E: out[t] = b_lin + sum_k H2[t][k]*w_lin[k]
// ---------------------------------------------------------------------------
__global__ void __launch_bounds__(256)
outs_kernel(const float* __restrict__ H2h, const float* __restrict__ wl,
            const float* __restrict__ bl, float* __restrict__ out)
{
    const int t = blockIdx.x;
    const int tid = threadIdx.x;
    const float* h = H2h + (size_t)t * HD + tid * 8;
    const float* wp = wl + tid * 8;
    float4 h0 = LD4(h), h1 = LD4(h + 4);
    float4 w0 = LD4(wp), w1 = LD4(wp + 4);
    float s = h0.x * w0.x;
    s = fmaf(h0.y, w0.y, s); s = fmaf(h0.z, w0.z, s); s = fmaf(h0.w, w0.w, s);
    s = fmaf(h1.x, w1.x, s); s = fmaf(h1.y, w1.y, s);
    s = fmaf(h1.z, w1.z, s); s = fmaf(h1.w, w1.w, s);
    #pragma unroll
    for (int off = 32; off > 0; off >>= 1) s += __shfl_down(s, off, 64);
    __shared__ float red[4];
    if ((tid & 63) == 0) red[tid >> 6] = s;
    __syncthreads();
    if (tid == 0) out[t] = red[0] + red[1] + red[2] + red[3] + bl[0];
}

// ---------------------------------------------------------------------------
// Phase D: 128 coupled future steps; weights streamed from L3.
// ---------------------------------------------------------------------------
__global__ void __launch_bounds__(1024, 4)
future_kernel(const float* __restrict__ Whh1, const float* __restrict__ Wih2,
              const float* __restrict__ Whh2,
              const float* __restrict__ wih1,
              const float* __restrict__ bih1, const float* __restrict__ bhh1,
              const float* __restrict__ bih2, const float* __restrict__ bhh2,
              const float* __restrict__ wl, const float* __restrict__ bl,
              u32* __restrict__ flags1, u32* __restrict__ vals1,
              u32* __restrict__ flags2, u32* __restrict__ vals2,
              const float* __restrict__ c1f, const float* __restrict__ c2f,
              float* __restrict__ out)
{
    __shared__ float lds_h1[HD];
    __shared__ float lds_h2[HD];
    __shared__ float lds_wl[HD];
    __shared__ float lds_p[32][33];
    __shared__ float lds_g[32];
    __shared__ float lds_red[17];

    const int tid = threadIdx.x;
    const int rl = tid >> 5;
    const int kl = tid & 31;
    const int gate = rl >> 3, jj = rl & 7;
    const int row = gate * HD + blockIdx.x * 8 + jj;
    const int e0 = tid * 2, e1 = tid * 2 + 1;
    const int wid = tid >> 6;
    const int lane = tid & 63;

    float rb1 = 0, rb2 = 0, raiv = 0;
    if (tid < 32) {
        int rg = tid >> 3, rj = tid & 7;
        int rr = rg * HD + blockIdx.x * 8 + rj;
        rb1 = bih1[rr] + bhh1[rr];
        rb2 = bih2[rr] + bhh2[rr];
        raiv = wih1[rr];
    }
    const float blin = bl[0];
    lds_wl[e0] = wl[e0]; lds_wl[e1] = wl[e1];

    float c1 = 0.0f, c2 = 0.0f;
    if (tid < 8) {
        c1 = c1f[blockIdx.x * 8 + tid];
        c2 = c2f[blockIdx.x * 8 + tid];
    }

    // prologue: stage h1(2047)  (flags1 already == 2048 after phase A)
    poll_flags(flags1, (u32)TT, tid);
    __syncthreads();
    {
        const u64* v64 = (const u64*)(vals1 + (size_t)((TT - 1) & 1) * HD);
        u64 v = __hip_atomic_load(v64 + tid, __ATOMIC_RELAXED, __HIP_MEMORY_SCOPE_AGENT);
        lds_h1[e0] = __uint_as_float((u32)v);
        lds_h1[e1] = __uint_as_float((u32)(v >> 32));
    }
    // (first in-loop barrier orders these writes before first GEMV1 reads)

    #pragma unroll 1
    for (int t = TT; t < TT + FUT; ++t) {
        // stage h2(t-1)
        poll_flags(flags2, (u32)t, tid);
        __syncthreads();
        {
            const u64* v64 = (const u64*)(vals2 + (size_t)((t - 1) & 1) * HD);
            u64 v = __hip_atomic_load(v64 + tid, __ATOMIC_RELAXED, __HIP_MEMORY_SCOPE_AGENT);
            lds_h2[e0] = __uint_as_float((u32)v);
            lds_h2[e1] = __uint_as_float((u32)(v >> 32));
        }
        __syncthreads();

        // out(t-1) = w_lin . h2(t-1) + b_lin  (redundant, bitwise-identical)
        float s = fmaf(lds_wl[e0], lds_h2[e0], lds_wl[e1] * lds_h2[e1]);
        #pragma unroll
        for (int off = 32; off > 0; off >>= 1) s += __shfl_down(s, off, 64);
        if (lane == 0) lds_red[wid] = s;
        __syncthreads();
        float xcur;
        {
            float ss = 0;
            #pragma unroll
            for (int i2 = 0; i2 < 16; ++i2) ss += lds_red[i2];
            xcur = ss + blin;
        }
        if (t > TT && tid == 0 && blockIdx.x == 0) out[t - 1] = xcur;

        // GEMV1: gates1 = Whh1 @ h1(t-1)
        {
            const float* wr = Whh1 + (size_t)row * HD + kl * 4;
            const float* hb = lds_h1 + kl * 4;
            float a0 = 0, a1 = 0, a2 = 0, a3 = 0;
            #pragma unroll
            for (int q = 0; q < 16; ++q) {
                float4 wv = LD4(wr + q * 128);
                float4 hv = LD4(hb + q * 128);
                a0 = fmaf(wv.x, hv.x, a0); a1 = fmaf(wv.y, hv.y, a1);
                a2 = fmaf(wv.z, hv.z, a2); a3 = fmaf(wv.w, hv.w, a3);
            }
            lds_p[rl][kl] = (a0 + a1) + (a2 + a3);
        }
        __syncthreads();
        if (tid < 32) {
            float s0 = 0, s1 = 0, s2 = 0, s3 = 0;
            #pragma unroll
            for (int cc = 0; cc < 32; cc += 4) {
                s0 += lds_p[tid][cc + 0]; s1 += lds_p[tid][cc + 1];
                s2 += lds_p[tid][cc + 2]; s3 += lds_p[tid][cc + 3];
            }
            float g1 = (s0 + s1) + (s2 + s3) + rb1 + raiv * xcur;
            lds_g[tid] = ((tid >> 3) == 2) ? tanh_(g1) : sigm_(g1);
            if (tid < 8) {
                float gi = lds_g[tid], gf = lds_g[8 + tid];
                float gg = lds_g[16 + tid], go = lds_g[24 + tid];
                c1 = gf * c1 + gi * gg;
                float h = go * tanh_(c1);
                __hip_atomic_store(vals1 + (size_t)(t & 1) * HD + blockIdx.x * 8 + tid,
                                   __float_as_uint(h), __ATOMIC_RELAXED, __HIP_MEMORY_SCOPE_AGENT);
            }
        }
        if (tid == 0)
            __hip_atomic_store(flags1 + blockIdx.x, (u32)(t + 1),
                               __ATOMIC_RELEASE, __HIP_MEMORY_SCOPE_AGENT);

        // stage h1(t)
        poll_flags(flags1, (u32)(t + 1), tid);
        __syncthreads();
        {
            const u64* v64 = (const u64*)(vals1 + (size_t)(t & 1) * HD);
            u64 v = __hip_atomic_load(v64 + tid, __ATOMIC_RELAXED, __HIP_MEMORY_SCOPE_AGENT);
            lds_h1[e0] = __uint_as_float((u32)v);
            lds_h1[e1] = __uint_as_float((u32)(v >> 32));
        }
        __syncthreads();

        // GEMV2: gates2 = Wih2 @ h1(t) + Whh2 @ h2(t-1)
        {
            const float* wr1 = Wih2 + (size_t)row * HD + kl * 4;
            const float* wr2 = Whh2 + (size_t)row * HD + kl * 4;
            const float* hb1 = lds_h1 + kl * 4;
            const float* hb2 = lds_h2 + kl * 4;
            float a0 = 0, a1 = 0, a2 = 0, a3 = 0;
            #pragma unroll
            for (int q = 0; q < 16; ++q) {
                float4 wv = LD4(wr1 + q * 128);
                float4 hv = LD4(hb1 + q * 128);
                a0 = fmaf(wv.x, hv.x, a0); a1 = fmaf(wv.y, hv.y, a1);
                a2 = fmaf(wv.z, hv.z, a2); a3 = fmaf(wv.w, hv.w, a3);
            }
            #pragma unroll
            for (int q = 0; q < 16; ++q) {
                float4 wv = LD4(wr2 + q * 128);
                float4 hv = LD4(hb2 + q * 128);
                a0 = fmaf(wv.x, hv.x, a0); a1 = fmaf(wv.y, hv.y, a1);
                a2 = fmaf(wv.z, hv.z, a2); a3 = fmaf(wv.w, hv.w, a3);
            }
            lds_p[rl][kl] = (a0 + a1) + (a2 + a3);
        }
        __syncthreads();
        if (tid < 32) {
            float s0 = 0, s1 = 0, s2 = 0, s3 = 0;
            #pragma unroll
            for (int cc = 0; cc < 32; cc += 4) {
                s0 += lds_p[tid][cc + 0]; s1 += lds_p[tid][cc + 1];
                s2 += lds_p[tid][cc + 2]; s3 += lds_p[tid][cc + 3];
            }
            float g2 = (s0 + s1) + (s2 + s3) + rb2;
            lds_g[tid] = ((tid >> 3) == 2) ? tanh_(g2) : sigm_(g2);
            if (tid < 8) {
                float gi = lds_g[tid], gf = lds_g[8 + tid];
                float gg = lds_g[16 + tid], go = lds_g[24 + tid];
                c2 = gf * c2 + gi * gg;
                float h = go * tanh_(c2);
                __hip_atomic_store(vals2 + (size_t)(t & 1) * HD + blockIdx.x * 8 + tid,
                                   __float_as_uint(h), __ATOMIC_RELAXED, __HIP_MEMORY_SCOPE_AGENT);
            }
        }
        if (tid == 0)
            __hip_atomic_store(flags2 + blockIdx.x, (u32)(t + 1),
                               __ATOMIC_RELEASE, __HIP_MEMORY_SCOPE_AGENT);
    }

    // epilogue: out(2175)
    poll_flags(flags2, (u32)(TT + FUT), tid);
    __syncthreads();
    {
        const u64* v64 = (const u64*)(vals2 + (size_t)((TT + FUT - 1) & 1) * HD);
        u64 v = __hip_atomic_load(v64 + tid, __ATOMIC_RELAXED, __HIP_MEMORY_SCOPE_AGENT);
        lds_h2[e0] = __uint_as_float((u32)v);
        lds_h2[e1] = __uint_as_float((u32)(v >> 32));
    }
    __syncthreads();
    float s = fmaf(lds_wl[e0], lds_h2[e0], lds_wl[e1] * lds_h2[e1]);
    #pragma unroll
    for (int off = 32; off > 0; off >>= 1) s += __shfl_down(s, off, 64);
    if (lane == 0) lds_red[wid] = s;
    __syncthreads();
    if (tid == 0 && blockIdx.x == 0) {
        float ss = 0;
        #pragma unroll
        for (int i2 = 0; i2 < 16; ++i2) ss += lds_red[i2];
        out[TT + FUT - 1] = ss + blin;
    }
}

// ---------------------------------------------------------------------------

extern "C" void kernel_launch(void* const* d_in, const int* in_sizes, int n_in,
                              void* d_out, int out_size, void* d_ws, size_t ws_size,
                              hipStream_t stream) {
    const float* input = (const float*)d_in[0];
    const float* w_ih1 = (const float*)d_in[1];
    const float* w_hh1 = (const float*)d_in[2];
    const float* b_ih1 = (const float*)d_in[3];
    const float* b_hh1 = (const float*)d_in[4];
    const float* w_ih2 = (const float*)d_in[5];
    const float* w_hh2 = (const float*)d_in[6];
    const float* b_ih2 = (const float*)d_in[7];
    const float* b_hh2 = (const float*)d_in[8];
    const float* w_lin = (const float*)d_in[9];
    const float* b_lin = (const float*)d_in[10];
    float* out = (float*)d_out;

    char* ws = (char*)d_ws;
    u32*   flags1 = (u32*)(ws);
    u32*   flags2 = (u32*)(ws + 4096);
    u32*   vals1  = (u32*)(ws + 8192);
    u32*   vals2  = (u32*)(ws + 32768);
    float* H1   = (float*)(ws + 65536);
    float* H2   = (float*)(ws + 65536 + (size_t)16 * 1024 * 1024);
    float* IG2  = (float*)(ws + 65536 + (size_t)32 * 1024 * 1024);
    float* c1f  = (float*)(ws + 65536 + (size_t)96 * 1024 * 1024);
    float* c2f  = (float*)(ws + 65536 + (size_t)96 * 1024 * 1024 + 8192);

    // ---- init: zero flags (ws is poisoned 0xAA; 0xAAAAAAAA would pass >= polls)
    hipLaunchKernelGGL(init_flags_kernel, dim3(8), dim3(256), 0, stream, (u32*)ws);

    // ---- Phase A: layer-1 recurrence ----
    {
        const float* Wrec = w_hh1; const float* aiv = w_ih1;
        const float* ba = b_ih1;   const float* bb = b_hh1;
        const float* xs = input;   const float* ig = nullptr;
        u32* fl = flags1; u32* vl = vals1; float* hh = H1; float* cf = c1f;
        void* args[] = {&Wrec, &aiv, &ba, &bb, &xs, &ig, &fl, &vl, &hh, &cf};
        if (hipLaunchCooperativeKernel((const void*)recur_kernel, dim3(256), dim3(1024),
                                       args, 0, stream) != hipSuccess) {
            (void)hipGetLastError();
            hipLaunchKernelGGL(recur_kernel, dim3(256), dim3(1024), 0, stream,
                               Wrec, aiv, ba, bb, xs, ig, fl, vl, hh, cf);
        }
    }

    // ---- Phase B: IG2 = W_ih2 @ H1^T ----
    hipLaunchKernelGGL(ig2_gemm_kernel, dim3(G4 / 128, TT / 128), dim3(256), 0, stream,
                       H1, w_ih2, IG2);

    // ---- Phase C: layer-2 recurrence ----
    {
        const float* Wrec = w_hh2; const float* aiv = nullptr;
        const float* ba = b_ih2;   const float* bb = b_hh2;
        const float* xs = nullptr; const float* ig = IG2;
        u32* fl = flags2; u32* vl = vals2; float* hh = H2; float* cf = c2f;
        void* args[] = {&Wrec, &aiv, &ba, &bb, &xs, &ig, &fl, &vl, &hh, &cf};
        if (hipLaunchCooperativeKernel((const void*)recur_kernel, dim3(256), dim3(1024),
                                       args, 0, stream) != hipSuccess) {
            (void)hipGetLastError();
            hipLaunchKernelGGL(recur_kernel, dim3(256), dim3(1024), 0, stream,
                               Wrec, aiv, ba, bb, xs, ig, fl, vl, hh, cf);
        }
    }

    // ---- Phase E: out[0..2047] ----
    hipLaunchKernelGGL(outs_kernel, dim3(TT), dim3(256), 0, stream, H2, w_lin, b_lin, out);

    // ---- Phase D: 128 future steps ----
    {
        const float* a0 = w_hh1; const float* a1 = w_ih2; const float* a2 = w_hh2;
        const float* a3 = w_ih1;
        const float* a4 = b_ih1; const float* a5 = b_hh1;
        const float* a6 = b_ih2; const float* a7 = b_hh2;
        const float* a8 = w_lin; const float* a9 = b_lin;
        u32* f1 = flags1; u32* v1 = vals1; u32* f2 = flags2; u32* v2 = vals2;
        const float* a12 = c1f; const float* a13 = c2f;
        float* a14 = out;
        void* args[] = {&a0, &a1, &a2, &a3, &a4, &a5, &a6, &a7, &a8, &a9,
                        &f1, &v1, &f2, &v2, &a12, &a13, &a14};
        if (hipLaunchCooperativeKernel((const void*)future_kernel, dim3(256), dim3(1024),
                                       args, 0, stream) != hipSuccess) {
            (void)hipGetLastError();
            hipLaunchKernelGGL(future_kernel, dim3(256), dim3(1024), 0, stream,
                               a0, a1, a2, a3, a4, a5, a6, a7, a8, a9,
                               f1, v1, f2, v2, a12, a13, a14);
        }
    }
}

// Round 3
// 19631.267 us; speedup vs baseline: 1.4687x; 1.4687x over previous
//
#include <hip/hip_runtime.h>
#include <stdint.h>

// LSTM: 2-layer LSTMCell H=2048, T=2048, future=128.
// R3: R1's 1-hop epoch-tagged exchange + asm-pinned VGPR-resident weights.
//
// Workspace layout (~97 MB):
//   h1ex  [2][2048] u64   @ 0        (value|epoch packed exchange, layer1)
//   h2ex  [2][2048] u64   @ 32768
//   H1    [2048][2048] f32 @ 65536
//   H2    [2048][2048] f32 @ 65536+16M
//   IG2   [2048][8192] f32 @ 65536+32M
//   c1f   [2048] f32       @ 65536+96M
//   c2f   [2048] f32       @ 65536+96M+8192

typedef unsigned long long u64;
typedef unsigned int u32;

#define HD 2048
#define TT 2048
#define FUT 128
#define G4 8192

#define LD4(p) (*reinterpret_cast<const float4*>(p))

__device__ __forceinline__ float sigm_(float x) {
    return 1.0f / (1.0f + __expf(-x));
}
__device__ __forceinline__ float tanh_(float x) {
    float xc = fminf(fmaxf(x, -15.0f), 15.0f);
    float e = __expf(2.0f * xc);
    return 1.0f - 2.0f / (e + 1.0f);
}

// Poll two epoch-tagged slots until tag matches; bounded to avoid hangs.
// Self-validating: value and tag share one u64 (atomic 8B load) -> 1 hop.
__device__ __forceinline__ void poll2(u64* p0, u64* p1, u32 tag,
                                      float* o0, float* o1, int* alive) {
    u64 v0 = 0, v1 = 0;
    int d0 = 0, d1 = 0, guard = 0;
    while (*alive) {
        if (!d0) { v0 = __hip_atomic_load(p0, __ATOMIC_RELAXED, __HIP_MEMORY_SCOPE_AGENT); d0 = ((u32)(v0 >> 32) == tag); }
        if (!d1) { v1 = __hip_atomic_load(p1, __ATOMIC_RELAXED, __HIP_MEMORY_SCOPE_AGENT); d1 = ((u32)(v1 >> 32) == tag); }
        if (d0 & d1) break;
        __builtin_amdgcn_s_sleep(2);
        if (++guard > (1 << 21)) *alive = 0;   // fail visibly, never hang
    }
    *o0 = __uint_as_float((u32)v0);
    *o1 = __uint_as_float((u32)v1);
}

__device__ __forceinline__ void publish1(u64* p, float v, u32 tag) {
    u64 pk = ((u64)tag << 32) | (u64)__float_as_uint(v);
    __hip_atomic_store(p, pk, __ATOMIC_RELAXED, __HIP_MEMORY_SCOPE_AGENT);
}

// Optimization barrier: force x to live in a VGPR at this point; the asm
// result cannot be rematerialized/sunk into the loop by LLVM.
#define KEEPF(x) asm volatile("" : "+v"(x))
#define KEEP4(W) do { KEEPF(W.x); KEEPF(W.y); KEEPF(W.z); KEEPF(W.w); } while (0)

// ---------------------------------------------------------------------------
// Phase A / C: one-layer recurrence with register-resident weights.
// 256 blocks x 1024 threads, 1 block/CU. Block b owns h outputs j=b*8..b*8+7
// (32 gate rows). Thread (chunk=tid>>5, br=tid&31) holds 64 weights of
// row(br) at cols chunk*64..chunk*64+63.
// ---------------------------------------------------------------------------
__global__ void __launch_bounds__(1024, 4)
recur_kernel(const float* __restrict__ Wrec,
             const float* __restrict__ aiv,     // w_ih1 or nullptr
             const float* __restrict__ ba,
             const float* __restrict__ bb,
             const float* __restrict__ xseq,    // input or nullptr
             const float* __restrict__ ig2,     // nullptr or [TT][G4]
             u64* __restrict__ hex,
             float* __restrict__ hist,
             float* __restrict__ cfin)
{
    __shared__ float lds_h[HD];
    __shared__ float lds_p[32][33];
    __shared__ float lds_g[32];
    __shared__ float lds_x[TT];

    const int tid = threadIdx.x;
    const int br = tid & 31;
    const int chunk = tid >> 5;
    const int gate = br >> 3;
    const int jj = br & 7;
    const int row = gate * HD + blockIdx.x * 8 + jj;
    const int e0 = tid * 2, e1 = tid * 2 + 1;

    // one-time resident weight load (64 fp32 / thread), pinned via asm barrier
    const float* wsrc = Wrec + (size_t)row * HD + chunk * 64;
    float4 w0  = LD4(wsrc +  0), w1  = LD4(wsrc +  4), w2  = LD4(wsrc +  8), w3  = LD4(wsrc + 12);
    float4 w4  = LD4(wsrc + 16), w5  = LD4(wsrc + 20), w6  = LD4(wsrc + 24), w7  = LD4(wsrc + 28);
    float4 w8  = LD4(wsrc + 32), w9  = LD4(wsrc + 36), w10 = LD4(wsrc + 40), w11 = LD4(wsrc + 44);
    float4 w12 = LD4(wsrc + 48), w13 = LD4(wsrc + 52), w14 = LD4(wsrc + 56), w15 = LD4(wsrc + 60);
    KEEP4(w0);  KEEP4(w1);  KEEP4(w2);  KEEP4(w3);
    KEEP4(w4);  KEEP4(w5);  KEEP4(w6);  KEEP4(w7);
    KEEP4(w8);  KEEP4(w9);  KEEP4(w10); KEEP4(w11);
    KEEP4(w12); KEEP4(w13); KEEP4(w14); KEEP4(w15);

    const float myb = ba[row] + bb[row];
    const float myaiv = aiv ? aiv[row] : 0.0f;

    if (xseq) { lds_x[e0] = xseq[e0]; lds_x[e1] = xseq[e1]; }

    float c = 0.0f;        // cell state: wave0 lanes 0..7
    int alive = 1;

    #pragma unroll 1
    for (int t = 0; t < TT; ++t) {
        // prefetch add-in early (independent of h staging)
        float addv = 0.0f;
        if (ig2 && tid < 32) addv = ig2[(size_t)t * G4 + row];

        // stage h(t-1)
        if (t == 0) {
            lds_h[e0] = 0.0f; lds_h[e1] = 0.0f;
        } else {
            u64* src = hex + (size_t)((t - 1) & 1) * HD;
            poll2(src + e0, src + e1, (u32)t, &lds_h[e0], &lds_h[e1], &alive);
        }
        __syncthreads();
        if (!ig2 && tid < 32) addv = myaiv * lds_x[t];

        // partial dot (h broadcast from LDS vs resident weights)
        const float* hc = lds_h + chunk * 64;
        float a0 = 0, a1 = 0, a2 = 0, a3 = 0;
        #define ACC4(W, i) { float4 hv = LD4(hc + 4 * (i)); \
            a0 = fmaf(W.x, hv.x, a0); a1 = fmaf(W.y, hv.y, a1); \
            a2 = fmaf(W.z, hv.z, a2); a3 = fmaf(W.w, hv.w, a3); }
        ACC4(w0, 0)   ACC4(w1, 1)   ACC4(w2, 2)   ACC4(w3, 3)
        ACC4(w4, 4)   ACC4(w5, 5)   ACC4(w6, 6)   ACC4(w7, 7)
        ACC4(w8, 8)   ACC4(w9, 9)   ACC4(w10, 10) ACC4(w11, 11)
        ACC4(w12, 12) ACC4(w13, 13) ACC4(w14, 14) ACC4(w15, 15)
        #undef ACC4
        lds_p[chunk][br] = (a0 + a1) + (a2 + a3);
        __syncthreads();

        if (tid < 32) {   // wave0: reduce 32 chunks, activate, cell update, publish
            float s0 = 0, s1 = 0, s2 = 0, s3 = 0;
            #pragma unroll
            for (int cc = 0; cc < 32; cc += 4) {
                s0 += lds_p[cc + 0][br];
                s1 += lds_p[cc + 1][br];
                s2 += lds_p[cc + 2][br];
                s3 += lds_p[cc + 3][br];
            }
            float gsum = (s0 + s1) + (s2 + s3) + myb + addv;
            lds_g[br] = (gate == 2) ? tanh_(gsum) : sigm_(gsum);
            // same wave: ds_write by lanes 0..31 precedes reads below in order
            if (br < 8) {
                float gi = lds_g[br], gf = lds_g[8 + br];
                float gg = lds_g[16 + br], go = lds_g[24 + br];
                c = gf * c + gi * gg;
                float h = go * tanh_(c);
                hist[(size_t)t * HD + blockIdx.x * 8 + br] = h;
                publish1(hex + (size_t)(t & 1) * HD + blockIdx.x * 8 + br, h, (u32)(t + 1));
            }
        }
    }
    if (tid < 8) cfin[blockIdx.x * 8 + tid] = c;
}

// ---------------------------------------------------------------------------
// Phase B: IG2[t][r] = sum_k H1[t][k] * W_ih2[r][k]  (fp32, 128x128 tile,
// BK=16, register prefetch double-buffering)
// ---------------------------------------------------------------------------
__global__ void __launch_bounds__(256)
ig2_gemm_kernel(const float* __restrict__ H1h, const float* __restrict__ W,
                float* __restrict__ IG2)
{
    __shared__ float As[16][132];
    __shared__ float Bs[16][132];
    const int tid = threadIdx.x;
    const int tx = tid & 15;
    const int ty = tid >> 4;
    const int r0 = blockIdx.x * 128;
    const int t0 = blockIdx.y * 128;
    const int stt = tid & 127;
    const int skc = tid >> 7;
    const int kb = skc * 8;

    float acc[8][8];
    #pragma unroll
    for (int i = 0; i < 8; ++i)
        #pragma unroll
        for (int j = 0; j < 8; ++j) acc[i][j] = 0.0f;

    const float* pa = H1h + (size_t)(t0 + stt) * HD + kb;
    const float* pb = W   + (size_t)(r0 + stt) * HD + kb;
    float4 va0 = LD4(pa), va1 = LD4(pa + 4);
    float4 vb0 = LD4(pb), vb1 = LD4(pb + 4);
    pa += 16; pb += 16;

    #pragma unroll 1
    for (int k0 = 0; k0 < HD; k0 += 16) {
        __syncthreads();   // previous tile's readers done
        As[kb + 0][stt] = va0.x; As[kb + 1][stt] = va0.y; As[kb + 2][stt] = va0.z; As[kb + 3][stt] = va0.w;
        As[kb + 4][stt] = va1.x; As[kb + 5][stt] = va1.y; As[kb + 6][stt] = va1.z; As[kb + 7][stt] = va1.w;
        Bs[kb + 0][stt] = vb0.x; Bs[kb + 1][stt] = vb0.y; Bs[kb + 2][stt] = vb0.z; Bs[kb + 3][stt] = vb0.w;
        Bs[kb + 4][stt] = vb1.x; Bs[kb + 5][stt] = vb1.y; Bs[kb + 6][stt] = vb1.z; Bs[kb + 7][stt] = vb1.w;
        __syncthreads();
        if (k0 + 16 < HD) {   // prefetch next tile into regs; hidden under FMAs
            va0 = LD4(pa); va1 = LD4(pa + 4);
            vb0 = LD4(pb); vb1 = LD4(pb + 4);
            pa += 16; pb += 16;
        }
        #pragma unroll
        for (int kk = 0; kk < 16; ++kk) {
            float4 fa0 = LD4(&As[kk][ty * 8]);
            float4 fa1 = LD4(&As[kk][ty * 8 + 4]);
            float4 fb0 = LD4(&Bs[kk][tx * 8]);
            float4 fb1 = LD4(&Bs[kk][tx * 8 + 4]);
            float av[8] = {fa0.x, fa0.y, fa0.z, fa0.w, fa1.x, fa1.y, fa1.z, fa1.w};
            float bv[8] = {fb0.x, fb0.y, fb0.z, fb0.w, fb1.x, fb1.y, fb1.z, fb1.w};
            #pragma unroll
            for (int i = 0; i < 8; ++i)
                #pragma unroll
                for (int j = 0; j < 8; ++j)
                    acc[i][j] = fmaf(av[i], bv[j], acc[i][j]);
        }
    }
    #pragma unroll
    for (int i = 0; i < 8; ++i) {
        float* pc = IG2 + (size_t)(t0 + ty * 8 + i) * G4 + (r0 + tx * 8);
        *reinterpret_cast<float4*>(pc)     = make_float4(acc[i][0], acc[i][1], acc[i][2], acc[i][3]);
        *reinterpret_cast<float4*>(pc + 4) = make_float4(acc[i][4], acc[i][5], acc[i][6], acc[i][7]);
    }
}

// ---------------------------------------------------------------------------
// Phase E: out[t] = b_lin + sum_k H2[t][k]*w_lin[k]
// ---------------------------------------------------------------------------
__global__ void __launch_bounds__(256)
outs_kernel(const float* __restrict__ H2h, const float* __restrict__ wl,
            const float* __restrict__ bl, float* __restrict__ out)
{
    const int t = blockIdx.x;
    const int tid = threadIdx.x;
    const float* h = H2h + (size_t)t * HD + tid * 8;
    const float* wp = wl + tid * 8;
    float4 h0 = LD4(h), h1 = LD4(h + 4);
    float4 w0 = LD4(wp), w1 = LD4(wp + 4);
    float s = h0.x * w0.x;
    s = fmaf(h0.y, w0.y, s); s = fmaf(h0.z, w0.z, s); s = fmaf(h0.w, w0.w, s);
    s = fmaf(h1.x, w1.x, s); s = fmaf(h1.y, w1.y, s);
    s = fmaf(h1.z, w1.z, s); s = fmaf(h1.w, w1.w, s);
    #pragma unroll
    for (int off = 32; off > 0; off >>= 1) s += __shfl_down(s, off, 64);
    __shared__ float red[4];
    if ((tid & 63) == 0) red[tid >> 6] = s;
    __syncthreads();
    if (tid == 0) out[t] = red[0] + red[1] + red[2] + red[3] + bl[0];
}

// ---------------------------------------------------------------------------
// Phase D: 128 coupled future steps; weights streamed from L3.
// 256x1024 cooperative shape; out(t) computed redundantly per block.
// ---------------------------------------------------------------------------
__global__ void __launch_bounds__(1024, 4)
future_kernel(const float* __restrict__ Whh1, const float* __restrict__ Wih2,
              const float* __restrict__ Whh2,
              const float* __restrict__ wih1,
              const float* __restrict__ bih1, const float* __restrict__ bhh1,
              const float* __restrict__ bih2, const float* __restrict__ bhh2,
              const float* __restrict__ wl, const float* __restrict__ bl,
              u64* __restrict__ h1ex, u64* __restrict__ h2ex,
              const float* __restrict__ c1f, const float* __restrict__ c2f,
              float* __restrict__ out)
{
    __shared__ float lds_h1[HD];
    __shared__ float lds_h2[HD];
    __shared__ float lds_wl[HD];
    __shared__ float lds_p[32][33];
    __shared__ float lds_g[32];
    __shared__ float lds_red[17];

    const int tid = threadIdx.x;
    const int rl = tid >> 5;       // row_local for streamed GEMV
    const int kl = tid & 31;
    const int gate = rl >> 3, jj = rl & 7;
    const int row = gate * HD + blockIdx.x * 8 + jj;
    const int e0 = tid * 2, e1 = tid * 2 + 1;
    const int wid = tid >> 6;
    const int lane = tid & 63;

    float rb1 = 0, rb2 = 0, raiv = 0;
    if (tid < 32) {
        int rg = tid >> 3, rj = tid & 7;
        int rr = rg * HD + blockIdx.x * 8 + rj;
        rb1 = bih1[rr] + bhh1[rr];
        rb2 = bih2[rr] + bhh2[rr];
        raiv = wih1[rr];
    }
    const float blin = bl[0];
    lds_wl[e0] = wl[e0]; lds_wl[e1] = wl[e1];

    float c1 = 0.0f, c2 = 0.0f;
    if (tid < 8) {
        c1 = c1f[blockIdx.x * 8 + tid];
        c2 = c2f[blockIdx.x * 8 + tid];
    }
    int alive = 1;

    // prologue: stage h1(2047) from phase A (slot 1, tag 2048)
    poll2(h1ex + HD + e0, h1ex + HD + e1, (u32)TT, &lds_h1[e0], &lds_h1[e1], &alive);

    #pragma unroll 1
    for (int t = TT; t < TT + FUT; ++t) {
        // stage h2(t-1): slot (t-1)&1, tag t
        {
            u64* src = h2ex + (size_t)((t - 1) & 1) * HD;
            poll2(src + e0, src + e1, (u32)t, &lds_h2[e0], &lds_h2[e1], &alive);
        }
        __syncthreads();

        // out(t-1) = w_lin . h2(t-1) + b_lin  (redundant, bitwise-identical)
        float s = fmaf(lds_wl[e0], lds_h2[e0], lds_wl[e1] * lds_h2[e1]);
        #pragma unroll
        for (int off = 32; off > 0; off >>= 1) s += __shfl_down(s, off, 64);
        if (lane == 0) lds_red[wid] = s;
        __syncthreads();
        float xcur;
        {
            float ss = 0;
            #pragma unroll
            for (int i2 = 0; i2 < 16; ++i2) ss += lds_red[i2];
            xcur = ss + blin;
        }
        if (t > TT && tid == 0 && blockIdx.x == 0) out[t - 1] = xcur;

        // GEMV1: gates1 = Whh1 @ h1(t-1)   (streamed from L3)
        {
            const float* wr = Whh1 + (size_t)row * HD + kl * 4;
            const float* hb = lds_h1 + kl * 4;
            float a0 = 0, a1 = 0, a2 = 0, a3 = 0;
            #pragma unroll
            for (int q = 0; q < 16; ++q) {
                float4 wv = LD4(wr + q * 128);
                float4 hv = LD4(hb + q * 128);
                a0 = fmaf(wv.x, hv.x, a0); a1 = fmaf(wv.y, hv.y, a1);
                a2 = fmaf(wv.z, hv.z, a2); a3 = fmaf(wv.w, hv.w, a3);
            }
            lds_p[rl][kl] = (a0 + a1) + (a2 + a3);
        }
        __syncthreads();
        if (tid < 32) {
            float s0 = 0, s1 = 0, s2 = 0, s3 = 0;
            #pragma unroll
            for (int cc = 0; cc < 32; cc += 4) {
                s0 += lds_p[tid][cc + 0]; s1 += lds_p[tid][cc + 1];
                s2 += lds_p[tid][cc + 2]; s3 += lds_p[tid][cc + 3];
            }
            float g1 = (s0 + s1) + (s2 + s3) + rb1 + raiv * xcur;
            lds_g[tid] = ((tid >> 3) == 2) ? tanh_(g1) : sigm_(g1);
            if (tid < 8) {
                float gi = lds_g[tid], gf = lds_g[8 + tid];
                float gg = lds_g[16 + tid], go = lds_g[24 + tid];
                c1 = gf * c1 + gi * gg;
                float h = go * tanh_(c1);
                publish1(h1ex + (size_t)(t & 1) * HD + blockIdx.x * 8 + tid, h, (u32)(t + 1));
            }
        }
        // stage h1(t)
        {
            u64* src = h1ex + (size_t)(t & 1) * HD;
            poll2(src + e0, src + e1, (u32)(t + 1), &lds_h1[e0], &lds_h1[e1], &alive);
        }
        __syncthreads();

        // GEMV2: gates2 = Wih2 @ h1(t) + Whh2 @ h2(t-1)   (streamed)
        {
            const float* wr1 = Wih2 + (size_t)row * HD + kl * 4;
            const float* wr2 = Whh2 + (size_t)row * HD + kl * 4;
            const float* hb1 = lds_h1 + kl * 4;
            const float* hb2 = lds_h2 + kl * 4;
            float a0 = 0, a1 = 0, a2 = 0, a3 = 0;
            #pragma unroll
            for (int q = 0; q < 16; ++q) {
                float4 wv = LD4(wr1 + q * 128);
                float4 hv = LD4(hb1 + q * 128);
                a0 = fmaf(wv.x, hv.x, a0); a1 = fmaf(wv.y, hv.y, a1);
                a2 = fmaf(wv.z, hv.z, a2); a3 = fmaf(wv.w, hv.w, a3);
            }
            #pragma unroll
            for (int q = 0; q < 16; ++q) {
                float4 wv = LD4(wr2 + q * 128);
                float4 hv = LD4(hb2 + q * 128);
                a0 = fmaf(wv.x, hv.x, a0); a1 = fmaf(wv.y, hv.y, a1);
                a2 = fmaf(wv.z, hv.z, a2); a3 = fmaf(wv.w, hv.w, a3);
            }
            lds_p[rl][kl] = (a0 + a1) + (a2 + a3);
        }
        __syncthreads();
        if (tid < 32) {
            float s0 = 0, s1 = 0, s2 = 0, s3 = 0;
            #pragma unroll
            for (int cc = 0; cc < 32; cc += 4) {
                s0 += lds_p[tid][cc + 0]; s1 += lds_p[tid][cc + 1];
                s2 += lds_p[tid][cc + 2]; s3 += lds_p[tid][cc + 3];
            }
            float g2 = (s0 + s1) + (s2 + s3) + rb2;
            lds_g[tid] = ((tid >> 3) == 2) ? tanh_(g2) : sigm_(g2);
            if (tid < 8) {
                float gi = lds_g[tid], gf = lds_g[8 + tid];
                float gg = lds_g[16 + tid], go = lds_g[24 + tid];
                c2 = gf * c2 + gi * gg;
                float h = go * tanh_(c2);
                publish1(h2ex + (size_t)(t & 1) * HD + blockIdx.x * 8 + tid, h, (u32)(t + 1));
            }
        }
    }

    // epilogue: out(2175) from h2(2175)
    {
        u64* src = h2ex + (size_t)((TT + FUT - 1) & 1) * HD;
        poll2(src + e0, src + e1, (u32)(TT + FUT), &lds_h2[e0], &lds_h2[e1], &alive);
    }
    __syncthreads();
    float s = fmaf(lds_wl[e0], lds_h2[e0], lds_wl[e1] * lds_h2[e1]);
    #pragma unroll
    for (int off = 32; off > 0; off >>= 1) s += __shfl_down(s, off, 64);
    if (lane == 0) lds_red[wid] = s;
    __syncthreads();
    if (tid == 0 && blockIdx.x == 0) {
        float ss = 0;
        #pragma unroll
        for (int i2 = 0; i2 < 16; ++i2) ss += lds_red[i2];
        out[TT + FUT - 1] = ss + blin;
    }
}

// ---------------------------------------------------------------------------

extern "C" void kernel_launch(void* const* d_in, const int* in_sizes, int n_in,
                              void* d_out, int out_size, void* d_ws, size_t ws_size,
                              hipStream_t stream) {
    const float* input = (const float*)d_in[0];
    const float* w_ih1 = (const float*)d_in[1];
    const float* w_hh1 = (const float*)d_in[2];
    const float* b_ih1 = (const float*)d_in[3];
    const float* b_hh1 = (const float*)d_in[4];
    const float* w_ih2 = (const float*)d_in[5];
    const float* w_hh2 = (const float*)d_in[6];
    const float* b_ih2 = (const float*)d_in[7];
    const float* b_hh2 = (const float*)d_in[8];
    const float* w_lin = (const float*)d_in[9];
    const float* b_lin = (const float*)d_in[10];
    float* out = (float*)d_out;

    char* ws = (char*)d_ws;
    u64*   h1ex = (u64*)(ws);
    u64*   h2ex = (u64*)(ws + 32768);
    float* H1   = (float*)(ws + 65536);
    float* H2   = (float*)(ws + 65536 + (size_t)16 * 1024 * 1024);
    float* IG2  = (float*)(ws + 65536 + (size_t)32 * 1024 * 1024);
    float* c1f  = (float*)(ws + 65536 + (size_t)96 * 1024 * 1024);
    float* c2f  = (float*)(ws + 65536 + (size_t)96 * 1024 * 1024 + 8192);

    // ---- Phase A: layer-1 recurrence (cooperative) ----
    {
        const float* Wrec = w_hh1; const float* aiv = w_ih1;
        const float* ba = b_ih1;   const float* bb = b_hh1;
        const float* xs = input;   const float* ig = nullptr;
        u64* hx = h1ex; float* hh = H1; float* cf = c1f;
        void* args[] = {&Wrec, &aiv, &ba, &bb, &xs, &ig, &hx, &hh, &cf};
        if (hipLaunchCooperativeKernel((const void*)recur_kernel, dim3(256), dim3(1024),
                                       args, 0, stream) != hipSuccess) {
            (void)hipGetLastError();
            hipLaunchKernelGGL(recur_kernel, dim3(256), dim3(1024), 0, stream,
                               Wrec, aiv, ba, bb, xs, ig, hx, hh, cf);
        }
    }

    // ---- Phase B: IG2 = W_ih2 @ H1^T ----
    hipLaunchKernelGGL(ig2_gemm_kernel, dim3(G4 / 128, TT / 128), dim3(256), 0, stream,
                       H1, w_ih2, IG2);

    // ---- Phase C: layer-2 recurrence (cooperative) ----
    {
        const float* Wrec = w_hh2; const float* aiv = nullptr;
        const float* ba = b_ih2;   const float* bb = b_hh2;
        const float* xs = nullptr; const float* ig = IG2;
        u64* hx = h2ex; float* hh = H2; float* cf = c2f;
        void* args[] = {&Wrec, &aiv, &ba, &bb, &xs, &ig, &hx, &hh, &cf};
        if (hipLaunchCooperativeKernel((const void*)recur_kernel, dim3(256), dim3(1024),
                                       args, 0, stream) != hipSuccess) {
            (void)hipGetLastError();
            hipLaunchKernelGGL(recur_kernel, dim3(256), dim3(1024), 0, stream,
                               Wrec, aiv, ba, bb, xs, ig, hx, hh, cf);
        }
    }

    // ---- Phase E: out[0..2047] ----
    hipLaunchKernelGGL(outs_kernel, dim3(TT), dim3(256), 0, stream, H2, w_lin, b_lin, out);

    // ---- Phase D: 128 future steps (cooperative) ----
    {
        const float* a0 = w_hh1; const float* a1 = w_ih2; const float* a2 = w_hh2;
        const float* a3 = w_ih1;
        const float* a4 = b_ih1; const float* a5 = b_hh1;
        const float* a6 = b_ih2; const float* a7 = b_hh2;
        const float* a8 = w_lin; const float* a9 = b_lin;
        u64* a10 = h1ex; u64* a11 = h2ex;
        const float* a12 = c1f; const float* a13 = c2f;
        float* a14 = out;
        void* args[] = {&a0, &a1, &a2, &a3, &a4, &a5, &a6, &a7, &a8, &a9,
                        &a10, &a11, &a12, &a13, &a14};
        if (hipLaunchCooperativeKernel((const void*)future_kernel, dim3(256), dim3(1024),
                                       args, 0, stream) != hipSuccess) {
            (void)hipGetLastError();
            hipLaunchKernelGGL(future_kernel, dim3(256), dim3(1024), 0, stream,
                               a0, a1, a2, a3, a4, a5, a6, a7, a8, a9,
                               a10, a11, a12, a13, a14);
        }
    }
}